// Round 3
// baseline (342.150 us; speedup 1.0000x reference)
//
#include <hip/hip_runtime.h>
#include <hip/hip_bf16.h>
#include <math.h>

typedef __bf16 bf16;
typedef __attribute__((ext_vector_type(8))) __bf16 bf16x8;
typedef __attribute__((ext_vector_type(4))) __bf16 bf16x4;
typedef __attribute__((ext_vector_type(4))) short short4v;
typedef __attribute__((ext_vector_type(4))) float f32x4;

#define MFMA16(a,b,c)  __builtin_amdgcn_mfma_f32_16x16x32_bf16((a),(b),(c),0,0,0)
#define MFMAK16(a,b,c) __builtin_amdgcn_mfma_f32_16x16x16bf16_1k((a),(b),(c),0,0,0)

__device__ __forceinline__ void gload16(const void* gp, void* lp) {
  __builtin_amdgcn_global_load_lds(
      (const __attribute__((address_space(1))) void*)gp,
      (__attribute__((address_space(3))) void*)lp, 16, 0, 0);
}

// ---------------- x cast: fp32 -> bf16, 8 elems/thread ----------------
__global__ __launch_bounds__(256) void cast_x(
    const float* __restrict__ x, bf16* __restrict__ xb)
{
  size_t i = ((size_t)blockIdx.x*256 + threadIdx.x) * 8;
  f32x4 a = *(const f32x4*)(x+i);
  f32x4 b = *(const f32x4*)(x+i+4);
  bf16x8 o;
  #pragma unroll
  for (int j=0;j<4;j++) { o[j] = (bf16)a[j]; o[4+j] = (bf16)b[j]; }
  *(bf16x8*)(xb+i) = o;
}

// ---------------- transpose+cast: Wt[n][k] (bf16) = W[k][n] (fp32), up to 3 mats --------
__global__ __launch_bounds__(1024) void tr_cast(
    const float* __restrict__ w0, const float* __restrict__ w1,
    const float* __restrict__ w2, bf16* __restrict__ dst)
{
  __shared__ bf16 tile[64][65];
  const float* src = (blockIdx.z==0)?w0:(blockIdx.z==1)?w1:w2;
  bf16* d = dst + (size_t)blockIdx.z * (1024*1024);
  int x = threadIdx.x, y = threadIdx.y;
  int tc = blockIdx.x, tr = blockIdx.y;
  #pragma unroll
  for (int i=0;i<4;i++) {
    int r = y + i*16;
    tile[r][x] = (bf16)src[(size_t)(tr*64+r)*1024 + tc*64 + x];
  }
  __syncthreads();
  #pragma unroll
  for (int i=0;i<4;i++) {
    int r = y + i*16;
    d[(size_t)(tc*64+r)*1024 + tr*64 + x] = tile[x][r];
  }
}

// ---------------- v transpose: v[t][1024] -> vT[(b*16+h)*64+d][4096] ----------------
__global__ __launch_bounds__(1024) void v_tr(
    const bf16* __restrict__ v, bf16* __restrict__ vt)
{
  __shared__ bf16 tile[64][65];
  int x = threadIdx.x, y = threadIdx.y;
  int tt = blockIdx.x;             // t-tile 0..63 (within batch)
  int bh = blockIdx.y;             // 0..31
  int b = bh >> 4, h = bh & 15;
  const bf16* src = v + ((size_t)b*4096 + tt*64)*1024 + h*64;
  bf16* dst = vt + ((size_t)bh*64)*4096 + tt*64;
  #pragma unroll
  for (int i=0;i<4;i++) {
    int r = y + i*16;
    tile[r][x] = src[(size_t)r*1024 + x];
  }
  __syncthreads();
  #pragma unroll
  for (int i=0;i<4;i++) {
    int r = y + i*16;
    dst[(size_t)r*4096 + x] = tile[x][r];
  }
}

// ---------------- fused QKV GEMM, pure gload16 staging (m97 path) ----------------
// [q|k|v] = xb @ [WqT|WkT|WvT]^T + b.  A bf16, Bt bf16, N=3072.
// q output PRE-SCALED by 1/sqrt(Hd)*log2(e). Coalesced epilogue for all 3 mats.
__global__ __launch_bounds__(256) void gemm_qkv(
    const bf16* __restrict__ A, const bf16* __restrict__ Bt,
    const float* __restrict__ bq, const float* __restrict__ bk, const float* __restrict__ bv,
    bf16* __restrict__ q, bf16* __restrict__ k, bf16* __restrict__ v,
    int M, int K)
{
  __shared__ __align__(16) bf16 As[128*32];
  __shared__ __align__(16) bf16 Bs[128*32];
  const int tid  = threadIdx.x;
  const int wave = tid >> 6;
  const int lane = tid & 63;
  const int l15  = lane & 15;
  const int quad = lane >> 4;
  const int m0 = blockIdx.y * 128;
  const int n0 = blockIdx.x * 128;
  const int wm = (wave >> 1) * 64;
  const int wn = (wave & 1) * 64;
  const int srow = lane >> 2;
  const int scol = (lane & 3) * 8;

  f32x4 acc[4][4];
  #pragma unroll
  for (int i=0;i<4;i++)
    #pragma unroll
    for (int j=0;j<4;j++)
      acc[i][j] = (f32x4){0.f,0.f,0.f,0.f};

  for (int k0 = 0; k0 < K; k0 += 32) {
    __syncthreads();
    #pragma unroll
    for (int p=0;p<2;p++) {
      int c = p*4 + wave;
      int row = c*16 + srow;
      gload16(A  + (size_t)(m0+row)*K + k0 + scol, As + c*512);
      gload16(Bt + (size_t)(n0+row)*K + k0 + scol, Bs + c*512);
    }
    __syncthreads();
    bf16x8 af[4], bfr[4];
    #pragma unroll
    for (int t=0;t<4;t++) {
      af[t]  = *(const bf16x8*)(As + (wm + t*16 + l15)*32 + quad*8);
      bfr[t] = *(const bf16x8*)(Bs + (wn + t*16 + l15)*32 + quad*8);
    }
    #pragma unroll
    for (int mt=0;mt<4;mt++)
      #pragma unroll
      for (int nt=0;nt<4;nt++)
        acc[mt][nt] = MFMA16(af[mt], bfr[nt], acc[mt][nt]);
  }

  const int mat = n0 >> 10;
  const float* bsel = (mat==0) ? bq : (mat==1) ? bk : bv;
  bf16*       osel  = (mat==0) ? q  : (mat==1) ? k  : v;
  const float qsc   = (mat==0) ? 0.1803368801f : 1.0f;  // log2(e)/sqrt(64)
  #pragma unroll
  for (int nt=0;nt<4;nt++) {
    int col = n0 + wn + nt*16 + l15;
    int cw  = col & 1023;
    float bvv = bsel[cw];
    #pragma unroll
    for (int mt=0;mt<4;mt++) {
      int row = m0 + wm + mt*16 + quad*4;
      #pragma unroll
      for (int r=0;r<4;r++)
        osel[(size_t)(row + r)*1024 + cw] = (bf16)((acc[mt][nt][r] + bvv) * qsc);
    }
  }
}

// ---------------- final GEMM: out(fp32) = ao(bf16) @ WtO^T + bo ----------------
__global__ __launch_bounds__(256) void gemm_out(
    const bf16* __restrict__ A, const bf16* __restrict__ Bt,
    const float* __restrict__ bias, float* __restrict__ C,
    int M, int N, int K)
{
  __shared__ __align__(16) bf16 As[128*32];
  __shared__ __align__(16) bf16 Bs[128*32];
  const int tid  = threadIdx.x;
  const int wave = tid >> 6;
  const int lane = tid & 63;
  const int l15  = lane & 15;
  const int quad = lane >> 4;
  const int m0 = blockIdx.y * 128;
  const int n0 = blockIdx.x * 128;
  const int wm = (wave >> 1) * 64;
  const int wn = (wave & 1) * 64;
  const int srow = lane >> 2;
  const int scol = (lane & 3) * 8;

  f32x4 acc[4][4];
  #pragma unroll
  for (int i=0;i<4;i++)
    #pragma unroll
    for (int j=0;j<4;j++)
      acc[i][j] = (f32x4){0.f,0.f,0.f,0.f};

  for (int k0 = 0; k0 < K; k0 += 32) {
    __syncthreads();
    #pragma unroll
    for (int p=0;p<2;p++) {
      int c = p*4 + wave;
      int row = c*16 + srow;
      gload16(A  + (size_t)(m0+row)*K + k0 + scol, As + c*512);
      gload16(Bt + (size_t)(n0+row)*K + k0 + scol, Bs + c*512);
    }
    __syncthreads();
    bf16x8 af[4], bfr[4];
    #pragma unroll
    for (int t=0;t<4;t++) {
      af[t]  = *(const bf16x8*)(As + (wm + t*16 + l15)*32 + quad*8);
      bfr[t] = *(const bf16x8*)(Bs + (wn + t*16 + l15)*32 + quad*8);
    }
    #pragma unroll
    for (int mt=0;mt<4;mt++)
      #pragma unroll
      for (int nt=0;nt<4;nt++)
        acc[mt][nt] = MFMA16(af[mt], bfr[nt], acc[mt][nt]);
  }

  #pragma unroll
  for (int nt=0;nt<4;nt++) {
    int col = n0 + wn + nt*16 + l15;
    float bvv = bias[col];
    #pragma unroll
    for (int mt=0;mt<4;mt++) {
      int row = m0 + wm + mt*16 + quad*4;
      #pragma unroll
      for (int r=0;r<4;r++)
        C[(size_t)(row + r)*N + col] = acc[mt][nt][r] + bvv;
    }
  }
}

// ---------------- flash attention, S^T formulation, QBLK=128 ----------------
// R3: two 64-row Q-subtiles (A,B) per block share all K/V LDS reads and staging
// -> LDS bytes per unit work halved. K and V staged via global_load_lds with
// swizzle folded into the per-lane GLOBAL source address (LDS dest linear).
//   K LDS: byte(t,db) = t*128 + (db ^ ((t&7)<<4))       (16B-granular XOR)
//   V LDS: byte(d,tb) = d*128 + (tb ^ ((d&7)<<4))       (16B-granular XOR)
// V read (b64) bank check: bank-pair = (quad ^ ((l15&7)<<1) ^ (tt<<2))&15 ->
// uniform 4 lanes/bank-pair = throughput minimum, conflict-free.
// Causal: kt in [0, 2qt+1]; A diag @ kt==2qt, A dead @ kt==2qt+1, B diag @ ktmax.
// Balanced qt permutation keeps per-CU work constant under stride-256 CU model.
// O aliases Q: block-exclusive (row, head) slices, read-at-start/write-at-end.
__global__ __launch_bounds__(256, 4) void attn_fwd(
    const bf16* __restrict__ Q, const bf16* __restrict__ Kp,
    const bf16* __restrict__ Vtg, bf16* __restrict__ O)
{
  __shared__ __align__(16) char KsB[2*8192];
  __shared__ __align__(16) char VtB[2*8192];

  const int tid  = threadIdx.x;
  const int w    = tid >> 6;
  const int lane = tid & 63;
  const int l15  = lane & 15;
  const int quad = lane >> 4;

  const int bid = blockIdx.x;
  const int g  = bid >> 5;               // 0..31
  const int u  = g >> 3, vv = g & 7;
  const int qt = 8*u + ((u & 1) ? (7 - vv) : vv);   // balanced permutation
  const int bh = bid & 31;
  const int h  = bh & 15;
  const int b  = bh >> 4;

  const size_t headoff = (size_t)h * 64;
  const size_t bbase   = (size_t)b * 4096;
  const int q0 = qt * 128;

  bf16x8 aqA[2], aqB[2];
  {
    int rowA = q0 + w*16 + l15;
    const bf16* qp = Q + (bbase + rowA)*1024 + headoff + quad*8;
    aqA[0] = *(const bf16x8*)(qp);
    aqA[1] = *(const bf16x8*)(qp + 32);
    qp += 64*1024;
    aqB[0] = *(const bf16x8*)(qp);
    aqB[1] = *(const bf16x8*)(qp + 32);
  }

  short4v ones_s;
  {
    bf16x4 o1;
    #pragma unroll
    for (int j=0;j<4;j++) o1[j] = (bf16)1.0f;
    ones_s = __builtin_bit_cast(short4v, o1);
  }

  f32x4 accoA[4], accoB[4], accliA, accliB;
  #pragma unroll
  for (int i=0;i<4;i++) { accoA[i] = (f32x4){0.f,0.f,0.f,0.f}; accoB[i] = (f32x4){0.f,0.f,0.f,0.f}; }
  accliA = (f32x4){0.f,0.f,0.f,0.f};
  accliB = (f32x4){0.f,0.f,0.f,0.f};

  // ---- DMA staging lane geometry (wave w owns 16 rows: chunk pair 2w,2w+1) ----
  // LDS dest is linear base+lane*16; the XOR swizzle is applied to the GLOBAL src.
  const int lrow = 16*w + (lane >> 3);                  // K: t-row / V: d-row
  const int lcol = ((lane & 7) ^ (lane >> 3)) * 8;      // K: d-elem / V: t-elem
  const bf16* kgp = Kp  + (bbase + lrow)*1024 + headoff + lcol;
  const bf16* vgp = Vtg + ((size_t)(bh*64) + lrow)*4096 + lcol;
  char* const kb0 = KsB + w*2048;
  char* const vb0 = VtB + w*2048;

  // ---- read geometry ----
  const int s7    = l15 & 7;
  const int ks_r0 = l15*128 + ((quad ^ (s7 & 3)) << 4) + ((s7 >> 2) << 6);
  const int ks_r1 = ks_r0 ^ 64;
  const int vt_rb = l15*128 + ((quad << 3) ^ (s7 << 4));
  // vt read addr = nt*2048 + (vt_rb ^ (tt<<5))

  // ---- stage kt=0 into buf 0 ----
  gload16(kgp,            kb0);
  gload16(kgp + 8*1024,   kb0 + 1024);
  gload16(vgp,            vb0);
  gload16(vgp + 8*4096,   vb0 + 1024);
  __syncthreads();
  kgp += 64*1024;
  vgp += 64;

  const int ktmax = 2*qt + 1;
  for (int kt = 0; kt <= ktmax; ++kt) {
    const int p = kt & 1;
    if (kt < ktmax) {
      char* kb = KsB + (p^1)*8192 + w*2048;
      char* vb = VtB + (p^1)*8192 + w*2048;
      gload16(kgp,          kb);
      gload16(kgp + 8*1024, kb + 1024);
      gload16(vgp,          vb);
      gload16(vgp + 8*4096, vb + 1024);
      kgp += 64*1024;
      vgp += 64;
    }

    const char* ksb = KsB + p*8192;
    const char* vtb = VtB + p*8192;

    f32x4 accsA[4], accsB[4];
    #pragma unroll
    for (int i=0;i<4;i++) { accsA[i] = (f32x4){0.f,0.f,0.f,0.f}; accsB[i] = (f32x4){0.f,0.f,0.f,0.f}; }

    __builtin_amdgcn_s_setprio(1);
    #pragma unroll
    for (int kk=0;kk<2;kk++) {
      #pragma unroll
      for (int tt=0;tt<4;tt++) {
        bf16x8 ka = *(const bf16x8*)(ksb + (kk ? ks_r1 : ks_r0) + tt*2048);
        accsA[tt] = MFMA16(ka, aqA[kk], accsA[tt]);
        accsB[tt] = MFMA16(ka, aqB[kk], accsB[tt]);
      }
    }
    __builtin_amdgcn_s_setprio(0);

    const bool Adiag = (kt == 2*qt);
    const bool Adead = (kt >  2*qt);
    const bool Bdiag = (kt == ktmax);
    short4v ptsA[4], ptsB[4];
    #pragma unroll
    for (int tt=0;tt<4;tt++) {
      bf16x4 pa, pb;
      #pragma unroll
      for (int r=0;r<4;r++) {
        const bool tq = (tt*16 + quad*4 + r > w*16 + l15);
        float fa = __builtin_amdgcn_exp2f(fminf(accsA[tt][r], 60.0f));
        if (Adead || (Adiag && tq)) fa = 0.0f;
        float fb = __builtin_amdgcn_exp2f(fminf(accsB[tt][r], 60.0f));
        if (Bdiag && tq) fb = 0.0f;
        pa[r] = (bf16)fa; pb[r] = (bf16)fb;
      }
      ptsA[tt] = __builtin_bit_cast(short4v, pa);
      ptsB[tt] = __builtin_bit_cast(short4v, pb);
    }

    __builtin_amdgcn_s_setprio(1);
    #pragma unroll
    for (int nt=0;nt<4;nt++) {
      #pragma unroll
      for (int tt=0;tt<4;tt++) {
        bf16x4 va = *(const bf16x4*)(vtb + (vt_rb ^ (tt<<5)) + nt*2048);
        short4v vas = __builtin_bit_cast(short4v, va);
        accoA[nt] = MFMAK16(vas, ptsA[tt], accoA[nt]);
        accoB[nt] = MFMAK16(vas, ptsB[tt], accoB[nt]);
      }
    }
    #pragma unroll
    for (int tt=0;tt<4;tt++) {
      accliA = MFMAK16(ones_s, ptsA[tt], accliA);
      accliB = MFMAK16(ones_s, ptsB[tt], accliB);
    }
    __builtin_amdgcn_s_setprio(0);

    __syncthreads();
  }

  {
    float invA = 1.0f / accliA[0];
    float invB = 1.0f / accliB[0];
    int rowA = q0 + w*16 + l15;
    bf16* obA = O + (bbase + rowA)*1024 + headoff;
    bf16* obB = obA + 64*1024;
    #pragma unroll
    for (int nt=0;nt<4;nt++) {
      bf16x4 oA, oB;
      #pragma unroll
      for (int r=0;r<4;r++) {
        oA[r] = (bf16)(accoA[nt][r] * invA);
        oB[r] = (bf16)(accoB[nt][r] * invB);
      }
      *(bf16x4*)(obA + nt*16 + quad*4) = oA;
      *(bf16x4*)(obB + nt*16 + quad*4) = oB;
    }
  }
}

extern "C" void kernel_launch(void* const* d_in, const int* in_sizes, int n_in,
                              void* d_out, int out_size, void* d_ws, size_t ws_size,
                              hipStream_t stream) {
  const float* x  = (const float*)d_in[0];
  const float* Wq = (const float*)d_in[1];
  const float* bq = (const float*)d_in[2];
  const float* Wk = (const float*)d_in[3];
  const float* bk = (const float*)d_in[4];
  const float* Wv = (const float*)d_in[5];
  const float* bv = (const float*)d_in[6];
  const float* Wo = (const float*)d_in[7];
  const float* bo = (const float*)d_in[8];
  float* out = (float*)d_out;

  // ws (bf16 elems, 64 MB): q 8M | k 8M | v 8M | xb 8M.
  // ao in-place over q. WtO reuses xb after gemm_qkv.
  // d_out (32 MB) is scratch until gemm_out: WtQKV (6 MB) during gemm_qkv,
  // then vT (16 MB) written by v_tr (after gemm_qkv) and read by attn.
  bf16* ws = (bf16*)d_ws;
  bf16* q  = ws;
  bf16* k  = q + (size_t)8192*1024;
  bf16* v  = k + (size_t)8192*1024;
  bf16* xb = v + (size_t)8192*1024;
  bf16* ao = q;                      // in-place
  bf16* WtQKV = (bf16*)d_out;        // scratch: dead after gemm_qkv
  bf16* vT    = (bf16*)d_out;        // scratch: written after gemm_qkv, dead before gemm_out writes
  bf16* WtO   = xb;                  // xb dead after gemm_qkv

  tr_cast<<<dim3(16,16,3), dim3(64,16), 0, stream>>>(Wq, Wk, Wv, WtQKV);
  cast_x<<<4096, 256, 0, stream>>>(x, xb);
  gemm_qkv<<<dim3(24,64), 256, 0, stream>>>(xb, WtQKV, bq, bk, bv, q, k, v, 8192, 1024);
  v_tr<<<dim3(64,32), dim3(64,16), 0, stream>>>(v, vT);
  tr_cast<<<dim3(16,16,1), dim3(64,16), 0, stream>>>(Wo, Wo, Wo, WtO);
  attn_fwd<<<1024, 256, 0, stream>>>(q, k, vT, ao);
  gemm_out<<<dim3(8,64), 256, 0, stream>>>(ao, WtO, bo, out, 8192, 1024, 1024);
}

// Round 4
// 329.248 us; speedup vs baseline: 1.0392x; 1.0392x over previous
//
#include <hip/hip_runtime.h>
#include <hip/hip_bf16.h>
#include <math.h>

typedef __bf16 bf16;
typedef __attribute__((ext_vector_type(8))) __bf16 bf16x8;
typedef __attribute__((ext_vector_type(4))) __bf16 bf16x4;
typedef __attribute__((ext_vector_type(4))) short short4v;
typedef __attribute__((ext_vector_type(4))) float f32x4;

#define MFMA16(a,b,c)  __builtin_amdgcn_mfma_f32_16x16x32_bf16((a),(b),(c),0,0,0)
#define MFMAK16(a,b,c) __builtin_amdgcn_mfma_f32_16x16x16bf16_1k((a),(b),(c),0,0,0)

__device__ __forceinline__ void gload16(const void* gp, void* lp) {
  __builtin_amdgcn_global_load_lds(
      (const __attribute__((address_space(1))) void*)gp,
      (__attribute__((address_space(3))) void*)lp, 16, 0, 0);
}

// ---------------- x cast: fp32 -> bf16, 8 elems/thread ----------------
__global__ __launch_bounds__(256) void cast_x(
    const float* __restrict__ x, bf16* __restrict__ xb)
{
  size_t i = ((size_t)blockIdx.x*256 + threadIdx.x) * 8;
  f32x4 a = *(const f32x4*)(x+i);
  f32x4 b = *(const f32x4*)(x+i+4);
  bf16x8 o;
  #pragma unroll
  for (int j=0;j<4;j++) { o[j] = (bf16)a[j]; o[4+j] = (bf16)b[j]; }
  *(bf16x8*)(xb+i) = o;
}

// ---------------- transpose+cast: Wt[n][k] (bf16) = W[k][n] (fp32), up to 3 mats --------
__global__ __launch_bounds__(1024) void tr_cast(
    const float* __restrict__ w0, const float* __restrict__ w1,
    const float* __restrict__ w2, bf16* __restrict__ dst)
{
  __shared__ bf16 tile[64][65];
  const float* src = (blockIdx.z==0)?w0:(blockIdx.z==1)?w1:w2;
  bf16* d = dst + (size_t)blockIdx.z * (1024*1024);
  int x = threadIdx.x, y = threadIdx.y;
  int tc = blockIdx.x, tr = blockIdx.y;
  #pragma unroll
  for (int i=0;i<4;i++) {
    int r = y + i*16;
    tile[r][x] = (bf16)src[(size_t)(tr*64+r)*1024 + tc*64 + x];
  }
  __syncthreads();
  #pragma unroll
  for (int i=0;i<4;i++) {
    int r = y + i*16;
    d[(size_t)(tc*64+r)*1024 + tr*64 + x] = tile[x][r];
  }
}

// ---------------- v transpose: v[t][1024] -> vT[(b*16+h)*64+d][4096] ----------------
__global__ __launch_bounds__(1024) void v_tr(
    const bf16* __restrict__ v, bf16* __restrict__ vt)
{
  __shared__ bf16 tile[64][65];
  int x = threadIdx.x, y = threadIdx.y;
  int tt = blockIdx.x;             // t-tile 0..63 (within batch)
  int bh = blockIdx.y;             // 0..31
  int b = bh >> 4, h = bh & 15;
  const bf16* src = v + ((size_t)b*4096 + tt*64)*1024 + h*64;
  bf16* dst = vt + ((size_t)bh*64)*4096 + tt*64;
  #pragma unroll
  for (int i=0;i<4;i++) {
    int r = y + i*16;
    tile[r][x] = src[(size_t)r*1024 + x];
  }
  __syncthreads();
  #pragma unroll
  for (int i=0;i<4;i++) {
    int r = y + i*16;
    dst[(size_t)r*4096 + x] = tile[x][r];
  }
}

// ---------------- fused QKV GEMM, pure gload16 staging (m97 path) ----------------
// [q|k|v] = xb @ [WqT|WkT|WvT]^T + b.  A bf16, Bt bf16, N=3072.
// q output PRE-SCALED by 1/sqrt(Hd)*log2(e). Coalesced epilogue for all 3 mats.
__global__ __launch_bounds__(256) void gemm_qkv(
    const bf16* __restrict__ A, const bf16* __restrict__ Bt,
    const float* __restrict__ bq, const float* __restrict__ bk, const float* __restrict__ bv,
    bf16* __restrict__ q, bf16* __restrict__ k, bf16* __restrict__ v,
    int M, int K)
{
  __shared__ __align__(16) bf16 As[128*32];
  __shared__ __align__(16) bf16 Bs[128*32];
  const int tid  = threadIdx.x;
  const int wave = tid >> 6;
  const int lane = tid & 63;
  const int l15  = lane & 15;
  const int quad = lane >> 4;
  const int m0 = blockIdx.y * 128;
  const int n0 = blockIdx.x * 128;
  const int wm = (wave >> 1) * 64;
  const int wn = (wave & 1) * 64;
  const int srow = lane >> 2;
  const int scol = (lane & 3) * 8;

  f32x4 acc[4][4];
  #pragma unroll
  for (int i=0;i<4;i++)
    #pragma unroll
    for (int j=0;j<4;j++)
      acc[i][j] = (f32x4){0.f,0.f,0.f,0.f};

  for (int k0 = 0; k0 < K; k0 += 32) {
    __syncthreads();
    #pragma unroll
    for (int p=0;p<2;p++) {
      int c = p*4 + wave;
      int row = c*16 + srow;
      gload16(A  + (size_t)(m0+row)*K + k0 + scol, As + c*512);
      gload16(Bt + (size_t)(n0+row)*K + k0 + scol, Bs + c*512);
    }
    __syncthreads();
    bf16x8 af[4], bfr[4];
    #pragma unroll
    for (int t=0;t<4;t++) {
      af[t]  = *(const bf16x8*)(As + (wm + t*16 + l15)*32 + quad*8);
      bfr[t] = *(const bf16x8*)(Bs + (wn + t*16 + l15)*32 + quad*8);
    }
    #pragma unroll
    for (int mt=0;mt<4;mt++)
      #pragma unroll
      for (int nt=0;nt<4;nt++)
        acc[mt][nt] = MFMA16(af[mt], bfr[nt], acc[mt][nt]);
  }

  const int mat = n0 >> 10;
  const float* bsel = (mat==0) ? bq : (mat==1) ? bk : bv;
  bf16*       osel  = (mat==0) ? q  : (mat==1) ? k  : v;
  const float qsc   = (mat==0) ? 0.1803368801f : 1.0f;  // log2(e)/sqrt(64)
  #pragma unroll
  for (int nt=0;nt<4;nt++) {
    int col = n0 + wn + nt*16 + l15;
    int cw  = col & 1023;
    float bvv = bsel[cw];
    #pragma unroll
    for (int mt=0;mt<4;mt++) {
      int row = m0 + wm + mt*16 + quad*4;
      #pragma unroll
      for (int r=0;r<4;r++)
        osel[(size_t)(row + r)*1024 + cw] = (bf16)((acc[mt][nt][r] + bvv) * qsc);
    }
  }
}

// ---------------- final GEMM: out(fp32) = ao(bf16) @ WtO^T + bo ----------------
__global__ __launch_bounds__(256) void gemm_out(
    const bf16* __restrict__ A, const bf16* __restrict__ Bt,
    const float* __restrict__ bias, float* __restrict__ C,
    int M, int N, int K)
{
  __shared__ __align__(16) bf16 As[128*32];
  __shared__ __align__(16) bf16 Bs[128*32];
  const int tid  = threadIdx.x;
  const int wave = tid >> 6;
  const int lane = tid & 63;
  const int l15  = lane & 15;
  const int quad = lane >> 4;
  const int m0 = blockIdx.y * 128;
  const int n0 = blockIdx.x * 128;
  const int wm = (wave >> 1) * 64;
  const int wn = (wave & 1) * 64;
  const int srow = lane >> 2;
  const int scol = (lane & 3) * 8;

  f32x4 acc[4][4];
  #pragma unroll
  for (int i=0;i<4;i++)
    #pragma unroll
    for (int j=0;j<4;j++)
      acc[i][j] = (f32x4){0.f,0.f,0.f,0.f};

  for (int k0 = 0; k0 < K; k0 += 32) {
    __syncthreads();
    #pragma unroll
    for (int p=0;p<2;p++) {
      int c = p*4 + wave;
      int row = c*16 + srow;
      gload16(A  + (size_t)(m0+row)*K + k0 + scol, As + c*512);
      gload16(Bt + (size_t)(n0+row)*K + k0 + scol, Bs + c*512);
    }
    __syncthreads();
    bf16x8 af[4], bfr[4];
    #pragma unroll
    for (int t=0;t<4;t++) {
      af[t]  = *(const bf16x8*)(As + (wm + t*16 + l15)*32 + quad*8);
      bfr[t] = *(const bf16x8*)(Bs + (wn + t*16 + l15)*32 + quad*8);
    }
    #pragma unroll
    for (int mt=0;mt<4;mt++)
      #pragma unroll
      for (int nt=0;nt<4;nt++)
        acc[mt][nt] = MFMA16(af[mt], bfr[nt], acc[mt][nt]);
  }

  #pragma unroll
  for (int nt=0;nt<4;nt++) {
    int col = n0 + wn + nt*16 + l15;
    float bvv = bias[col];
    #pragma unroll
    for (int mt=0;mt<4;mt++) {
      int row = m0 + wm + mt*16 + quad*4;
      #pragma unroll
      for (int r=0;r<4;r++)
        C[(size_t)(row + r)*N + col] = acc[mt][nt][r] + bvv;
    }
  }
}

// ---------------- flash attention, S^T formulation, complementary-qt pairing ----------------
// R4: back to the R2 per-tile structure (reg-staged K/V ds_writes, measured 0 bank
// conflicts; XOR-swizzled LDS reads). New: each block runs TWO sequential phases,
// qt = p and qt = 63-p  ->  every block executes exactly 65 inner iterations.
// Grid 1024 = exactly 4 blocks/CU, all uniform: zero tail, no backfill needed.
// Causal mask hoisted into a wave-uniform branch (only the diag iteration pays it).
// O aliases Q: each (qt, bh) row-slice is read-at-start / written-at-end by exactly
// one phase of one block, race-free.
__global__ __launch_bounds__(256, 4) void attn_fwd(
    const bf16* __restrict__ Q, const bf16* __restrict__ Kp,
    const bf16* __restrict__ Vtg, bf16* __restrict__ O)
{
  __shared__ __align__(16) char KsB[2*8192];  // [buf][t][d-bytes ^ ((t&7)<<4)]
  __shared__ __align__(16) char VtB[2*8192];  // [buf][d][t-bytes ^ ((d&15)<<3)]

  const int tid  = threadIdx.x;
  const int w    = tid >> 6;
  const int lane = tid & 63;
  const int l15  = lane & 15;
  const int quad = lane >> 4;

  const int bid = blockIdx.x;
  const int pp  = bid >> 5;          // pair index 0..31
  const int bh  = bid & 31;
  const int h   = bh & 15;
  const int b   = bh >> 4;

  const size_t headoff = (size_t)h * 64;
  const size_t bbase   = (size_t)b * 4096;

  short4v ones_s;
  {
    bf16x4 o1;
    #pragma unroll
    for (int j=0;j<4;j++) o1[j] = (bf16)1.0f;
    ones_s = __builtin_bit_cast(short4v, o1);
  }

  // ---- K staging geometry (byte offsets, hoisted once) ----
  const int kt_row = tid >> 2;
  const int kswz   = (kt_row & 7) << 4;
  const int ks_w0  = kt_row*128 + (((tid & 3)*32)      ^ kswz);
  const int ks_w1  = kt_row*128 + (((tid & 3)*32 + 16) ^ kswz);

  // ---- V staging geometry: thread owns (d=vd, t=vt0..vt0+15) of the tile ----
  const int vd  = tid >> 2;          // 0..63
  const int vt0 = (tid & 3) * 16;    // 0,16,32,48
  int vw[4];
  #pragma unroll
  for (int u=0;u<4;u++)
    vw[u] = vd*128 + (((vt0 + u*4)*2) ^ ((vd & 15) << 3));

  // ---- read geometry (XOR decomposed into per-lane base + compile-time imm) ----
  const int s7    = l15 & 7;
  const int ks_r0 = l15*128 + ((quad ^ (s7 & 3)) << 4) + ((s7 >> 2) << 6);
  const int ks_r1 = ks_r0 ^ 64;
  const int vt_rbase = l15*128 + ((quad ^ (l15 & 3)) << 3) + ((l15 >> 2) << 5);
  int vt_r[4];
  #pragma unroll
  for (int tt=0;tt<4;tt++) vt_r[tt] = vt_rbase ^ (tt << 5);

  const bf16* kbase0 = Kp  + (bbase + kt_row)*1024 + headoff + (tid & 3)*16;
  const bf16* vbase0 = Vtg + ((size_t)(bh*64) + vd)*4096 + vt0;

  for (int ph = 0; ph < 2; ++ph) {
    const int qt = ph ? (63 - pp) : pp;
    const int q0 = qt * 64;

    bf16x8 aq[2];
    {
      int row = q0 + w*16 + l15;
      const bf16* qp = Q + (bbase + row)*1024 + headoff + quad*8;
      aq[0] = *(const bf16x8*)(qp);
      aq[1] = *(const bf16x8*)(qp + 32);
    }

    f32x4 acco[4];
    f32x4 accli;
    #pragma unroll
    for (int i=0;i<4;i++) acco[i] = (f32x4){0.f,0.f,0.f,0.f};
    accli = (f32x4){0.f,0.f,0.f,0.f};

    __syncthreads();   // previous phase's readers done before buf0 overwrite
    {
      bf16x8 k0 = *(const bf16x8*)(kbase0);
      bf16x8 k1 = *(const bf16x8*)(kbase0 + 8);
      *(bf16x8*)(KsB + ks_w0) = k0;
      *(bf16x8*)(KsB + ks_w1) = k1;
      bf16x8 v0 = *(const bf16x8*)(vbase0);
      bf16x8 v1 = *(const bf16x8*)(vbase0 + 8);
      *(bf16x4*)(VtB + vw[0]) = __builtin_shufflevector(v0, v0, 0,1,2,3);
      *(bf16x4*)(VtB + vw[1]) = __builtin_shufflevector(v0, v0, 4,5,6,7);
      *(bf16x4*)(VtB + vw[2]) = __builtin_shufflevector(v1, v1, 0,1,2,3);
      *(bf16x4*)(VtB + vw[3]) = __builtin_shufflevector(v1, v1, 4,5,6,7);
    }
    __syncthreads();

    const bf16* kpref = kbase0 + 64*1024;
    const bf16* vpref = vbase0 + 64;

    for (int kt = 0; kt <= qt; ++kt) {
      const int p = kt & 1;
      const bool pre = (kt < qt);

      bf16x8 kr0, kr1, vr0, vr1;
      if (pre) {
        kr0 = *(const bf16x8*)(kpref);
        kr1 = *(const bf16x8*)(kpref + 8);
        vr0 = *(const bf16x8*)(vpref);
        vr1 = *(const bf16x8*)(vpref + 8);
        kpref += 64*1024;
        vpref += 64;
      }

      const char* ksb = KsB + p*8192;
      const char* vtb = VtB + p*8192;

      f32x4 accs[4];
      #pragma unroll
      for (int i=0;i<4;i++) accs[i] = (f32x4){0.f,0.f,0.f,0.f};

      __builtin_amdgcn_s_setprio(1);
      #pragma unroll
      for (int kk=0;kk<2;kk++) {
        #pragma unroll
        for (int tt=0;tt<4;tt++) {
          bf16x8 ka = *(const bf16x8*)(ksb + (kk ? ks_r1 : ks_r0) + tt*2048);
          accs[tt] = MFMA16(ka, aq[kk], accs[tt]);
        }
      }
      __builtin_amdgcn_s_setprio(0);

      short4v pts[4];
      if (kt == qt) {
        // diagonal tile: causal mask active (wave-uniform branch)
        #pragma unroll
        for (int tt=0;tt<4;tt++) {
          bf16x4 pb;
          #pragma unroll
          for (int r=0;r<4;r++) {
            float pf = __builtin_amdgcn_exp2f(fminf(accs[tt][r], 60.0f));
            if (tt*16 + quad*4 + r > w*16 + l15) pf = 0.0f;
            pb[r] = (bf16)pf;
          }
          pts[tt] = __builtin_bit_cast(short4v, pb);
        }
      } else {
        #pragma unroll
        for (int tt=0;tt<4;tt++) {
          bf16x4 pb;
          #pragma unroll
          for (int r=0;r<4;r++)
            pb[r] = (bf16)__builtin_amdgcn_exp2f(fminf(accs[tt][r], 60.0f));
          pts[tt] = __builtin_bit_cast(short4v, pb);
        }
      }

      __builtin_amdgcn_s_setprio(1);
      #pragma unroll
      for (int nt=0;nt<4;nt++) {
        #pragma unroll
        for (int tt=0;tt<4;tt++) {
          bf16x4 va = *(const bf16x4*)(vtb + vt_r[tt] + nt*2048);
          acco[nt] = MFMAK16(__builtin_bit_cast(short4v, va), pts[tt], acco[nt]);
        }
      }
      #pragma unroll
      for (int tt=0;tt<4;tt++)
        accli = MFMAK16(ones_s, pts[tt], accli);
      __builtin_amdgcn_s_setprio(0);

      if (pre) {
        char* ksn = KsB + (p^1)*8192;
        char* vtn = VtB + (p^1)*8192;
        *(bf16x8*)(ksn + ks_w0) = kr0;
        *(bf16x8*)(ksn + ks_w1) = kr1;
        *(bf16x4*)(vtn + vw[0]) = __builtin_shufflevector(vr0, vr0, 0,1,2,3);
        *(bf16x4*)(vtn + vw[1]) = __builtin_shufflevector(vr0, vr0, 4,5,6,7);
        *(bf16x4*)(vtn + vw[2]) = __builtin_shufflevector(vr1, vr1, 0,1,2,3);
        *(bf16x4*)(vtn + vw[3]) = __builtin_shufflevector(vr1, vr1, 4,5,6,7);
        __syncthreads();
      }
    }

    {
      float inv = 1.0f / accli[0];
      int qrow = q0 + w*16 + l15;
      bf16* ob = O + (bbase + qrow)*1024 + headoff;
      #pragma unroll
      for (int nt=0;nt<4;nt++) {
        bf16x4 o;
        #pragma unroll
        for (int r=0;r<4;r++) o[r] = (bf16)(acco[nt][r] * inv);
        *(bf16x4*)(ob + nt*16 + quad*4) = o;
      }
    }
  }
}

extern "C" void kernel_launch(void* const* d_in, const int* in_sizes, int n_in,
                              void* d_out, int out_size, void* d_ws, size_t ws_size,
                              hipStream_t stream) {
  const float* x  = (const float*)d_in[0];
  const float* Wq = (const float*)d_in[1];
  const float* bq = (const float*)d_in[2];
  const float* Wk = (const float*)d_in[3];
  const float* bk = (const float*)d_in[4];
  const float* Wv = (const float*)d_in[5];
  const float* bv = (const float*)d_in[6];
  const float* Wo = (const float*)d_in[7];
  const float* bo = (const float*)d_in[8];
  float* out = (float*)d_out;

  // ws (bf16 elems, 64 MB): q 8M | k 8M | v 8M | xb 8M.
  // ao in-place over q. WtO reuses xb after gemm_qkv.
  // d_out (32 MB) is scratch until gemm_out: WtQKV (6 MB) during gemm_qkv,
  // then vT (16 MB) written by v_tr (after gemm_qkv) and read by attn.
  bf16* ws = (bf16*)d_ws;
  bf16* q  = ws;
  bf16* k  = q + (size_t)8192*1024;
  bf16* v  = k + (size_t)8192*1024;
  bf16* xb = v + (size_t)8192*1024;
  bf16* ao = q;                      // in-place
  bf16* WtQKV = (bf16*)d_out;        // scratch: dead after gemm_qkv
  bf16* vT    = (bf16*)d_out;        // scratch: written after gemm_qkv, dead before gemm_out writes
  bf16* WtO   = xb;                  // xb dead after gemm_qkv

  tr_cast<<<dim3(16,16,3), dim3(64,16), 0, stream>>>(Wq, Wk, Wv, WtQKV);
  cast_x<<<4096, 256, 0, stream>>>(x, xb);
  gemm_qkv<<<dim3(24,64), 256, 0, stream>>>(xb, WtQKV, bq, bk, bv, q, k, v, 8192, 1024);
  v_tr<<<dim3(64,32), dim3(64,16), 0, stream>>>(v, vT);
  tr_cast<<<dim3(16,16,1), dim3(64,16), 0, stream>>>(Wo, Wo, Wo, WtO);
  attn_fwd<<<1024, 256, 0, stream>>>(q, k, vT, ao);
  gemm_out<<<dim3(8,64), 256, 0, stream>>>(ao, WtO, bo, out, 8192, 1024, 1024);
}

// Round 5
// 325.452 us; speedup vs baseline: 1.0513x; 1.0117x over previous
//
#include <hip/hip_runtime.h>
#include <hip/hip_bf16.h>
#include <math.h>

typedef __bf16 bf16;
typedef __attribute__((ext_vector_type(8))) __bf16 bf16x8;
typedef __attribute__((ext_vector_type(4))) __bf16 bf16x4;
typedef __attribute__((ext_vector_type(4))) short short4v;
typedef __attribute__((ext_vector_type(4))) float f32x4;

#define MFMA16(a,b,c)  __builtin_amdgcn_mfma_f32_16x16x32_bf16((a),(b),(c),0,0,0)
#define MFMAK16(a,b,c) __builtin_amdgcn_mfma_f32_16x16x16bf16_1k((a),(b),(c),0,0,0)

__device__ __forceinline__ void gload16(const void* gp, void* lp) {
  __builtin_amdgcn_global_load_lds(
      (const __attribute__((address_space(1))) void*)gp,
      (__attribute__((address_space(3))) void*)lp, 16, 0, 0);
}

// ---------------- x cast: fp32 -> bf16, 8 elems/thread ----------------
__global__ __launch_bounds__(256) void cast_x(
    const float* __restrict__ x, bf16* __restrict__ xb)
{
  size_t i = ((size_t)blockIdx.x*256 + threadIdx.x) * 8;
  f32x4 a = *(const f32x4*)(x+i);
  f32x4 b = *(const f32x4*)(x+i+4);
  bf16x8 o;
  #pragma unroll
  for (int j=0;j<4;j++) { o[j] = (bf16)a[j]; o[4+j] = (bf16)b[j]; }
  *(bf16x8*)(xb+i) = o;
}

// ---------------- transpose+cast: Wt[n][k] (bf16) = W[k][n] (fp32), up to 3 mats --------
__global__ __launch_bounds__(1024) void tr_cast(
    const float* __restrict__ w0, const float* __restrict__ w1,
    const float* __restrict__ w2, bf16* __restrict__ dst)
{
  __shared__ bf16 tile[64][65];
  const float* src = (blockIdx.z==0)?w0:(blockIdx.z==1)?w1:w2;
  bf16* d = dst + (size_t)blockIdx.z * (1024*1024);
  int x = threadIdx.x, y = threadIdx.y;
  int tc = blockIdx.x, tr = blockIdx.y;
  #pragma unroll
  for (int i=0;i<4;i++) {
    int r = y + i*16;
    tile[r][x] = (bf16)src[(size_t)(tr*64+r)*1024 + tc*64 + x];
  }
  __syncthreads();
  #pragma unroll
  for (int i=0;i<4;i++) {
    int r = y + i*16;
    d[(size_t)(tc*64+r)*1024 + tr*64 + x] = tile[x][r];
  }
}

// ---------------- v transpose: v[t][1024] -> vT[(b*16+h)*64+d][4096] ----------------
__global__ __launch_bounds__(1024) void v_tr(
    const bf16* __restrict__ v, bf16* __restrict__ vt)
{
  __shared__ bf16 tile[64][65];
  int x = threadIdx.x, y = threadIdx.y;
  int tt = blockIdx.x;             // t-tile 0..63 (within batch)
  int bh = blockIdx.y;             // 0..31
  int b = bh >> 4, h = bh & 15;
  const bf16* src = v + ((size_t)b*4096 + tt*64)*1024 + h*64;
  bf16* dst = vt + ((size_t)bh*64)*4096 + tt*64;
  #pragma unroll
  for (int i=0;i<4;i++) {
    int r = y + i*16;
    tile[r][x] = src[(size_t)r*1024 + x];
  }
  __syncthreads();
  #pragma unroll
  for (int i=0;i<4;i++) {
    int r = y + i*16;
    dst[(size_t)r*4096 + x] = tile[x][r];
  }
}

// ---------------- fused QKV GEMM, pure gload16 staging (m97 path) ----------------
// [q|k|v] = xb @ [WqT|WkT|WvT]^T + b.  A bf16, Bt bf16, N=3072.
// q output PRE-SCALED by 1/sqrt(Hd)*log2(e). Coalesced epilogue for all 3 mats.
__global__ __launch_bounds__(256) void gemm_qkv(
    const bf16* __restrict__ A, const bf16* __restrict__ Bt,
    const float* __restrict__ bq, const float* __restrict__ bk, const float* __restrict__ bv,
    bf16* __restrict__ q, bf16* __restrict__ k, bf16* __restrict__ v,
    int M, int K)
{
  __shared__ __align__(16) bf16 As[128*32];
  __shared__ __align__(16) bf16 Bs[128*32];
  const int tid  = threadIdx.x;
  const int wave = tid >> 6;
  const int lane = tid & 63;
  const int l15  = lane & 15;
  const int quad = lane >> 4;
  const int m0 = blockIdx.y * 128;
  const int n0 = blockIdx.x * 128;
  const int wm = (wave >> 1) * 64;
  const int wn = (wave & 1) * 64;
  const int srow = lane >> 2;
  const int scol = (lane & 3) * 8;

  f32x4 acc[4][4];
  #pragma unroll
  for (int i=0;i<4;i++)
    #pragma unroll
    for (int j=0;j<4;j++)
      acc[i][j] = (f32x4){0.f,0.f,0.f,0.f};

  for (int k0 = 0; k0 < K; k0 += 32) {
    __syncthreads();
    #pragma unroll
    for (int p=0;p<2;p++) {
      int c = p*4 + wave;
      int row = c*16 + srow;
      gload16(A  + (size_t)(m0+row)*K + k0 + scol, As + c*512);
      gload16(Bt + (size_t)(n0+row)*K + k0 + scol, Bs + c*512);
    }
    __syncthreads();
    bf16x8 af[4], bfr[4];
    #pragma unroll
    for (int t=0;t<4;t++) {
      af[t]  = *(const bf16x8*)(As + (wm + t*16 + l15)*32 + quad*8);
      bfr[t] = *(const bf16x8*)(Bs + (wn + t*16 + l15)*32 + quad*8);
    }
    #pragma unroll
    for (int mt=0;mt<4;mt++)
      #pragma unroll
      for (int nt=0;nt<4;nt++)
        acc[mt][nt] = MFMA16(af[mt], bfr[nt], acc[mt][nt]);
  }

  const int mat = n0 >> 10;
  const float* bsel = (mat==0) ? bq : (mat==1) ? bk : bv;
  bf16*       osel  = (mat==0) ? q  : (mat==1) ? k  : v;
  const float qsc   = (mat==0) ? 0.1803368801f : 1.0f;  // log2(e)/sqrt(64)
  #pragma unroll
  for (int nt=0;nt<4;nt++) {
    int col = n0 + wn + nt*16 + l15;
    int cw  = col & 1023;
    float bvv = bsel[cw];
    #pragma unroll
    for (int mt=0;mt<4;mt++) {
      int row = m0 + wm + mt*16 + quad*4;
      #pragma unroll
      for (int r=0;r<4;r++)
        osel[(size_t)(row + r)*1024 + cw] = (bf16)((acc[mt][nt][r] + bvv) * qsc);
    }
  }
}

// ---------------- final GEMM: out(fp32) = ao(bf16) @ WtO^T + bo ----------------
__global__ __launch_bounds__(256) void gemm_out(
    const bf16* __restrict__ A, const bf16* __restrict__ Bt,
    const float* __restrict__ bias, float* __restrict__ C,
    int M, int N, int K)
{
  __shared__ __align__(16) bf16 As[128*32];
  __shared__ __align__(16) bf16 Bs[128*32];
  const int tid  = threadIdx.x;
  const int wave = tid >> 6;
  const int lane = tid & 63;
  const int l15  = lane & 15;
  const int quad = lane >> 4;
  const int m0 = blockIdx.y * 128;
  const int n0 = blockIdx.x * 128;
  const int wm = (wave >> 1) * 64;
  const int wn = (wave & 1) * 64;
  const int srow = lane >> 2;
  const int scol = (lane & 3) * 8;

  f32x4 acc[4][4];
  #pragma unroll
  for (int i=0;i<4;i++)
    #pragma unroll
    for (int j=0;j<4;j++)
      acc[i][j] = (f32x4){0.f,0.f,0.f,0.f};

  for (int k0 = 0; k0 < K; k0 += 32) {
    __syncthreads();
    #pragma unroll
    for (int p=0;p<2;p++) {
      int c = p*4 + wave;
      int row = c*16 + srow;
      gload16(A  + (size_t)(m0+row)*K + k0 + scol, As + c*512);
      gload16(Bt + (size_t)(n0+row)*K + k0 + scol, Bs + c*512);
    }
    __syncthreads();
    bf16x8 af[4], bfr[4];
    #pragma unroll
    for (int t=0;t<4;t++) {
      af[t]  = *(const bf16x8*)(As + (wm + t*16 + l15)*32 + quad*8);
      bfr[t] = *(const bf16x8*)(Bs + (wn + t*16 + l15)*32 + quad*8);
    }
    #pragma unroll
    for (int mt=0;mt<4;mt++)
      #pragma unroll
      for (int nt=0;nt<4;nt++)
        acc[mt][nt] = MFMA16(af[mt], bfr[nt], acc[mt][nt]);
  }

  #pragma unroll
  for (int nt=0;nt<4;nt++) {
    int col = n0 + wn + nt*16 + l15;
    float bvv = bias[col];
    #pragma unroll
    for (int mt=0;mt<4;mt++) {
      int row = m0 + wm + mt*16 + quad*4;
      #pragma unroll
      for (int r=0;r<4;r++)
        C[(size_t)(row + r)*N + col] = acc[mt][nt][r] + bvv;
    }
  }
}

// ---------------- flash attention, S^T formulation, dual q-group + pairing ----------------
// R5: LDS-BW-bound fix. Each wave owns TWO 16-row q-groups (A: rows q0+w*16,
// B: rows q0+64+w*16) sharing every ka/va LDS read -> LDS bytes per unit work
// halved. Q-tiles are 128 rows; complementary pairing qt = {p, 31-p} makes every
// block exactly 66 iterations. Grid 512 = 2 blocks/CU uniform, zero tail.
// Staging is reg-staged ds_writes (R2 pattern, measured 0 bank conflicts);
// XOR-swizzled read layouts verbatim from R2. Masks only on kt >= 2qt iters.
// O aliases Q: block-exclusive (row, head) slices, read-at-start/write-at-end.
__global__ __launch_bounds__(256, 2) void attn_fwd(
    const bf16* __restrict__ Q, const bf16* __restrict__ Kp,
    const bf16* __restrict__ Vtg, bf16* __restrict__ O)
{
  __shared__ __align__(16) char KsB[2*8192];  // [buf][t][d-bytes ^ ((t&7)<<4)]
  __shared__ __align__(16) char VtB[2*8192];  // [buf][d][t-bytes ^ ((d&15)<<3)]

  const int tid  = threadIdx.x;
  const int w    = tid >> 6;
  const int lane = tid & 63;
  const int l15  = lane & 15;
  const int quad = lane >> 4;

  const int bid = blockIdx.x;
  const int pp  = bid >> 5;          // pair index 0..15
  const int bh  = bid & 31;
  const int h   = bh & 15;
  const int b   = bh >> 4;

  const size_t headoff = (size_t)h * 64;
  const size_t bbase   = (size_t)b * 4096;

  short4v ones_s;
  {
    bf16x4 o1;
    #pragma unroll
    for (int j=0;j<4;j++) o1[j] = (bf16)1.0f;
    ones_s = __builtin_bit_cast(short4v, o1);
  }

  // ---- K staging geometry (byte offsets, hoisted once) ----
  const int kt_row = tid >> 2;
  const int kswz   = (kt_row & 7) << 4;
  const int ks_w0  = kt_row*128 + (((tid & 3)*32)      ^ kswz);
  const int ks_w1  = kt_row*128 + (((tid & 3)*32 + 16) ^ kswz);

  // ---- V staging geometry: thread owns (d=vd, t=vt0..vt0+15) of the tile ----
  const int vd  = tid >> 2;          // 0..63
  const int vt0 = (tid & 3) * 16;    // 0,16,32,48
  int vw[4];
  #pragma unroll
  for (int u=0;u<4;u++)
    vw[u] = vd*128 + (((vt0 + u*4)*2) ^ ((vd & 15) << 3));

  // ---- read geometry (XOR decomposed into per-lane base + compile-time imm) ----
  const int s7    = l15 & 7;
  const int ks_r0 = l15*128 + ((quad ^ (s7 & 3)) << 4) + ((s7 >> 2) << 6);
  const int ks_r1 = ks_r0 ^ 64;
  const int vt_rbase = l15*128 + ((quad ^ (l15 & 3)) << 3) + ((l15 >> 2) << 5);
  int vt_r[4];
  #pragma unroll
  for (int tt=0;tt<4;tt++) vt_r[tt] = vt_rbase ^ (tt << 5);

  const bf16* kbase0 = Kp  + (bbase + kt_row)*1024 + headoff + (tid & 3)*16;
  const bf16* vbase0 = Vtg + ((size_t)(bh*64) + vd)*4096 + vt0;

  for (int ph = 0; ph < 2; ++ph) {
    const int qt = ph ? (31 - pp) : pp;
    const int q0 = qt * 128;
    const int ktmax = 2*qt + 1;

    bf16x8 aqA[2], aqB[2];
    {
      int rowA = q0 + w*16 + l15;
      const bf16* qp = Q + (bbase + rowA)*1024 + headoff + quad*8;
      aqA[0] = *(const bf16x8*)(qp);
      aqA[1] = *(const bf16x8*)(qp + 32);
      qp += 64*1024;
      aqB[0] = *(const bf16x8*)(qp);
      aqB[1] = *(const bf16x8*)(qp + 32);
    }

    f32x4 accoA[4], accoB[4], accliA, accliB;
    #pragma unroll
    for (int i=0;i<4;i++) { accoA[i] = (f32x4){0.f,0.f,0.f,0.f}; accoB[i] = (f32x4){0.f,0.f,0.f,0.f}; }
    accliA = (f32x4){0.f,0.f,0.f,0.f};
    accliB = (f32x4){0.f,0.f,0.f,0.f};

    __syncthreads();   // previous phase's readers done before buf0 overwrite
    {
      bf16x8 k0 = *(const bf16x8*)(kbase0);
      bf16x8 k1 = *(const bf16x8*)(kbase0 + 8);
      *(bf16x8*)(KsB + ks_w0) = k0;
      *(bf16x8*)(KsB + ks_w1) = k1;
      bf16x8 v0 = *(const bf16x8*)(vbase0);
      bf16x8 v1 = *(const bf16x8*)(vbase0 + 8);
      *(bf16x4*)(VtB + vw[0]) = __builtin_shufflevector(v0, v0, 0,1,2,3);
      *(bf16x4*)(VtB + vw[1]) = __builtin_shufflevector(v0, v0, 4,5,6,7);
      *(bf16x4*)(VtB + vw[2]) = __builtin_shufflevector(v1, v1, 0,1,2,3);
      *(bf16x4*)(VtB + vw[3]) = __builtin_shufflevector(v1, v1, 4,5,6,7);
    }
    __syncthreads();

    const bf16* kpref = kbase0 + 64*1024;
    const bf16* vpref = vbase0 + 64;

    for (int kt = 0; kt <= ktmax; ++kt) {
      const int p = kt & 1;
      const bool pre = (kt < ktmax);

      bf16x8 kr0, kr1, vr0, vr1;
      if (pre) {
        kr0 = *(const bf16x8*)(kpref);
        kr1 = *(const bf16x8*)(kpref + 8);
        vr0 = *(const bf16x8*)(vpref);
        vr1 = *(const bf16x8*)(vpref + 8);
        kpref += 64*1024;
        vpref += 64;
      }

      const char* ksb = KsB + p*8192;
      const char* vtb = VtB + p*8192;

      f32x4 accsA[4], accsB[4];
      #pragma unroll
      for (int i=0;i<4;i++) { accsA[i] = (f32x4){0.f,0.f,0.f,0.f}; accsB[i] = (f32x4){0.f,0.f,0.f,0.f}; }

      __builtin_amdgcn_s_setprio(1);
      #pragma unroll
      for (int kk=0;kk<2;kk++) {
        #pragma unroll
        for (int tt=0;tt<4;tt++) {
          bf16x8 ka = *(const bf16x8*)(ksb + (kk ? ks_r1 : ks_r0) + tt*2048);
          accsA[tt] = MFMA16(ka, aqA[kk], accsA[tt]);
          accsB[tt] = MFMA16(ka, aqB[kk], accsB[tt]);
        }
      }
      __builtin_amdgcn_s_setprio(0);

      short4v ptsA[4], ptsB[4];
      if (kt < 2*qt) {
        // common path: no masks
        #pragma unroll
        for (int tt=0;tt<4;tt++) {
          bf16x4 pa, pb;
          #pragma unroll
          for (int r=0;r<4;r++) {
            pa[r] = (bf16)__builtin_amdgcn_exp2f(fminf(accsA[tt][r], 60.0f));
            pb[r] = (bf16)__builtin_amdgcn_exp2f(fminf(accsB[tt][r], 60.0f));
          }
          ptsA[tt] = __builtin_bit_cast(short4v, pa);
          ptsB[tt] = __builtin_bit_cast(short4v, pb);
        }
      } else {
        // kt == 2qt: A diagonal, B plain.  kt == 2qt+1: A dead, B diagonal.
        const bool adead = (kt > 2*qt);
        #pragma unroll
        for (int tt=0;tt<4;tt++) {
          bf16x4 pa, pb;
          #pragma unroll
          for (int r=0;r<4;r++) {
            const bool tq = (tt*16 + quad*4 + r > w*16 + l15);
            float fa = __builtin_amdgcn_exp2f(fminf(accsA[tt][r], 60.0f));
            if (adead || tq) fa = 0.0f;
            float fb = __builtin_amdgcn_exp2f(fminf(accsB[tt][r], 60.0f));
            if (adead && tq) fb = 0.0f;
            pa[r] = (bf16)fa; pb[r] = (bf16)fb;
          }
          ptsA[tt] = __builtin_bit_cast(short4v, pa);
          ptsB[tt] = __builtin_bit_cast(short4v, pb);
        }
      }

      __builtin_amdgcn_s_setprio(1);
      #pragma unroll
      for (int nt=0;nt<4;nt++) {
        #pragma unroll
        for (int tt=0;tt<4;tt++) {
          bf16x4 va = *(const bf16x4*)(vtb + vt_r[tt] + nt*2048);
          short4v vas = __builtin_bit_cast(short4v, va);
          accoA[nt] = MFMAK16(vas, ptsA[tt], accoA[nt]);
          accoB[nt] = MFMAK16(vas, ptsB[tt], accoB[nt]);
        }
      }
      #pragma unroll
      for (int tt=0;tt<4;tt++) {
        accliA = MFMAK16(ones_s, ptsA[tt], accliA);
        accliB = MFMAK16(ones_s, ptsB[tt], accliB);
      }
      __builtin_amdgcn_s_setprio(0);

      if (pre) {
        char* ksn = KsB + (p^1)*8192;
        char* vtn = VtB + (p^1)*8192;
        *(bf16x8*)(ksn + ks_w0) = kr0;
        *(bf16x8*)(ksn + ks_w1) = kr1;
        *(bf16x4*)(vtn + vw[0]) = __builtin_shufflevector(vr0, vr0, 0,1,2,3);
        *(bf16x4*)(vtn + vw[1]) = __builtin_shufflevector(vr0, vr0, 4,5,6,7);
        *(bf16x4*)(vtn + vw[2]) = __builtin_shufflevector(vr1, vr1, 0,1,2,3);
        *(bf16x4*)(vtn + vw[3]) = __builtin_shufflevector(vr1, vr1, 4,5,6,7);
        __syncthreads();
      }
    }

    {
      float invA = 1.0f / accliA[0];
      float invB = 1.0f / accliB[0];
      int rowA = q0 + w*16 + l15;
      bf16* obA = O + (bbase + rowA)*1024 + headoff;
      bf16* obB = obA + 64*1024;
      #pragma unroll
      for (int nt=0;nt<4;nt++) {
        bf16x4 oA, oB;
        #pragma unroll
        for (int r=0;r<4;r++) {
          oA[r] = (bf16)(accoA[nt][r] * invA);
          oB[r] = (bf16)(accoB[nt][r] * invB);
        }
        *(bf16x4*)(obA + nt*16 + quad*4) = oA;
        *(bf16x4*)(obB + nt*16 + quad*4) = oB;
      }
    }
  }
}

extern "C" void kernel_launch(void* const* d_in, const int* in_sizes, int n_in,
                              void* d_out, int out_size, void* d_ws, size_t ws_size,
                              hipStream_t stream) {
  const float* x  = (const float*)d_in[0];
  const float* Wq = (const float*)d_in[1];
  const float* bq = (const float*)d_in[2];
  const float* Wk = (const float*)d_in[3];
  const float* bk = (const float*)d_in[4];
  const float* Wv = (const float*)d_in[5];
  const float* bv = (const float*)d_in[6];
  const float* Wo = (const float*)d_in[7];
  const float* bo = (const float*)d_in[8];
  float* out = (float*)d_out;

  // ws (bf16 elems, 64 MB): q 8M | k 8M | v 8M | xb 8M.
  // ao in-place over q. WtO reuses xb after gemm_qkv.
  // d_out (32 MB) is scratch until gemm_out: WtQKV (6 MB) during gemm_qkv,
  // then vT (16 MB) written by v_tr (after gemm_qkv) and read by attn.
  bf16* ws = (bf16*)d_ws;
  bf16* q  = ws;
  bf16* k  = q + (size_t)8192*1024;
  bf16* v  = k + (size_t)8192*1024;
  bf16* xb = v + (size_t)8192*1024;
  bf16* ao = q;                      // in-place
  bf16* WtQKV = (bf16*)d_out;        // scratch: dead after gemm_qkv
  bf16* vT    = (bf16*)d_out;        // scratch: written after gemm_qkv, dead before gemm_out writes
  bf16* WtO   = xb;                  // xb dead after gemm_qkv

  tr_cast<<<dim3(16,16,3), dim3(64,16), 0, stream>>>(Wq, Wk, Wv, WtQKV);
  cast_x<<<4096, 256, 0, stream>>>(x, xb);
  gemm_qkv<<<dim3(24,64), 256, 0, stream>>>(xb, WtQKV, bq, bk, bv, q, k, v, 8192, 1024);
  v_tr<<<dim3(64,32), dim3(64,16), 0, stream>>>(v, vT);
  tr_cast<<<dim3(16,16,1), dim3(64,16), 0, stream>>>(Wo, Wo, Wo, WtO);
  attn_fwd<<<512, 256, 0, stream>>>(q, k, vT, ao);
  gemm_out<<<dim3(8,64), 256, 0, stream>>>(ao, WtO, bo, out, 8192, 1024, 1024);
}